// Round 3
// baseline (750.391 us; speedup 1.0000x reference)
//
#include <hip/hip_runtime.h>
#include <math.h>

#define NB1 1024
#define BS  256

typedef float f4v __attribute__((ext_vector_type(4)));

__device__ __forceinline__ void nts4(float4* p, float4 v) {
    __builtin_nontemporal_store(*(const f4v*)&v, (f4v*)p);
}
__device__ __forceinline__ void nts1(float* p, float v) {
    __builtin_nontemporal_store(v, p);
}

// fast transcendentals (args constrained as noted; tolerance is 0.0625 absmax)
__device__ __forceinline__ float fast_tanh_pos(float x) {   // x >= 0
    float e = __expf(-2.f * x);
    return (1.f - e) / (1.f + e);
}
__device__ __forceinline__ float fast_atanh01(float x) {    // x in [0,1)
    return 0.5f * __logf((1.f + x) / (1.f - x));
}

// Computes per-row base quantities from mf = features[row][4:8]:
//   hp[8]  = hyp_pt   (hyperbolic point, exp-map from origin, projected)
//   sd[3]  = spd_diag (exp(linear)+0.1)
//   sp[8]  = sph_pt   (normalized sphere point)
__device__ __forceinline__ void compute_base(
    const float4 mf,
    const float* __restrict__ Wh, const float* __restrict__ bh,
    const float* __restrict__ Ws, const float* __restrict__ bs,
    const float* __restrict__ Wp, const float* __restrict__ bp,
    float* hp, float* sd, float* sp)
{
    // hyp_tan = mf[0:2] @ W_hyp + b_hyp ; hyp_pt = proj(tanh(|t|)/|t| * t)
    float ht[8];
    float nv2 = 0.f;
#pragma unroll
    for (int j = 0; j < 8; ++j) {
        float t = mf.x * Wh[j] + mf.y * Wh[8 + j] + bh[j];
        ht[j] = t; nv2 += t * t;
    }
    float nv = fmaxf(sqrtf(nv2), 1e-10f);
    float coef = fast_tanh_pos(nv) / nv;  // C=1: tanh(sc*lam*nv/2)/(sc*nv) with lam=2
    float pn2 = 0.f;
#pragma unroll
    for (int j = 0; j < 8; ++j) {
        float p = coef * ht[j];           // mobius_add(0,y)=y/(1+1e-10); den==1 in f32
        hp[j] = p; pn2 += p * p;
    }
    float pn = sqrtf(pn2);
    if (pn > 0.99999f) {                  // _hyp_proj, max_norm=(1-1e-5)
        float s = 0.99999f / pn;
#pragma unroll
        for (int j = 0; j < 8; ++j) hp[j] *= s;
    }
    // spd_diag = exp(mf[0:3] @ W_spd + b_spd) + 0.1
#pragma unroll
    for (int k = 0; k < 3; ++k) {
        float t = mf.x * Ws[k] + mf.y * Ws[3 + k] + mf.z * Ws[6 + k] + bs[k];
        sd[k] = __expf(t) + 0.1f;
    }
    // sph_pt = proj(mf[2:4] @ W_sph + b_sph)
    float sl[8]; float sn2 = 0.f;
#pragma unroll
    for (int j = 0; j < 8; ++j) {
        float t = mf.z * Wp[j] + mf.w * Wp[8 + j] + bp[j];
        sl[j] = t; sn2 += t * t;
    }
    float isn = 1.0f / (sqrtf(sn2) + 1e-10f);
#pragma unroll
    for (int j = 0; j < 8; ++j) sp[j] = sl[j] * isn;
}

// Pass 1: per-block partial sums of [hyp_pt(8), log(spd_diag+1e-8)(3), sph_pt(8)]
__global__ __launch_bounds__(BS) void reduce_kernel(
    const float* __restrict__ feat, int n,
    const float* __restrict__ Wh, const float* __restrict__ bh,
    const float* __restrict__ Ws, const float* __restrict__ bs,
    const float* __restrict__ Wp, const float* __restrict__ bp,
    float* __restrict__ partials)
{
    float acc[19];
#pragma unroll
    for (int i = 0; i < 19; ++i) acc[i] = 0.f;
    int stride = gridDim.x * blockDim.x;
    for (int row = blockIdx.x * blockDim.x + threadIdx.x; row < n; row += stride) {
        float4 mf = *(const float4*)(feat + (size_t)row * 8 + 4);
        float hp[8], sd[3], sp[8];
        compute_base(mf, Wh, bh, Ws, bs, Wp, bp, hp, sd, sp);
#pragma unroll
        for (int j = 0; j < 8; ++j) acc[j] += hp[j];
#pragma unroll
        for (int k = 0; k < 3; ++k) acc[8 + k] += __logf(sd[k] + 1e-8f);
#pragma unroll
        for (int j = 0; j < 8; ++j) acc[11 + j] += sp[j];
    }
#pragma unroll
    for (int i = 0; i < 19; ++i) {
#pragma unroll
        for (int off = 32; off >= 1; off >>= 1)
            acc[i] += __shfl_down(acc[i], off, 64);
    }
    __shared__ float red[4][19];
    int lane = threadIdx.x & 63, wid = threadIdx.x >> 6;
    if (lane == 0) {
#pragma unroll
        for (int i = 0; i < 19; ++i) red[wid][i] = acc[i];
    }
    __syncthreads();
    if (threadIdx.x < 19) {
        float s = red[0][threadIdx.x] + red[1][threadIdx.x] +
                  red[2][threadIdx.x] + red[3][threadIdx.x];
        partials[(size_t)blockIdx.x * 19 + threadIdx.x] = s;
    }
}

// Pass 2: f64 finalize of the three means -> 19 constants:
//   cons[0:8]=hc (hyp_proj of mean), cons[8:11]=geo_mean, cons[11:19]=sc (sph_proj of mean)
__global__ void finalize_kernel(const float* __restrict__ partials,
                                float* __restrict__ cons, int n)
{
    __shared__ double ms[19];
    int tid = threadIdx.x;
    int k = tid >> 3, w = tid & 7;
    if (k < 19) {
        double s = 0.0;
        for (int b = w; b < NB1; b += 8) s += (double)partials[(size_t)b * 19 + k];
#pragma unroll
        for (int off = 4; off >= 1; off >>= 1) s += __shfl_down(s, off, 8);
        if (w == 0) ms[k] = s / (double)n;
    }
    __syncthreads();
    if (tid == 0) {
        double hn2 = 0.0;
        for (int j = 0; j < 8; ++j) hn2 += ms[j] * ms[j];
        double hn = sqrt(hn2);
        double sch = (hn > 0.99999) ? (0.99999 / hn) : 1.0;
        for (int j = 0; j < 8; ++j) cons[j] = (float)(ms[j] * sch);
        for (int kk = 0; kk < 3; ++kk) cons[8 + kk] = (float)exp(ms[8 + kk]);
        double sn2 = 0.0;
        for (int j = 0; j < 8; ++j) sn2 += ms[11 + j] * ms[11 + j];
        double sn = sqrt(sn2) + 1e-10;
        for (int j = 0; j < 8; ++j) cons[11 + j] = (float)(ms[11 + j] / sn);
    }
}

// Pass 3a: geometry kernel. Computes hr/srd/sr/comb per row; writes
// hyp/spd/sph (non-temporal, LDS-staged coalesced) and comb (REGULAR stores so
// it stays L2/L3-resident for the integrated kernel that follows).
// LDS = 1604 float4 = 25664 B -> 6 blocks/CU.
__global__ __launch_bounds__(BS) void geom_kernel(
    const float* __restrict__ feat, int n,
    const float* __restrict__ Wh, const float* __restrict__ bh,
    const float* __restrict__ Ws, const float* __restrict__ bs,
    const float* __restrict__ Wp, const float* __restrict__ bp,
    const float* __restrict__ cons,
    float* __restrict__ out)
{
    __shared__ float4 sbuf4[1604];           // 25664 B, unioned across rounds
    float* sf = (float*)sbuf4;

    const int tid = threadIdx.x;
    const int blockStart = blockIdx.x * BS;
    const int row = blockStart + tid;
    const bool valid = row < n;
    const int vr = min(BS, n - blockStart);

    float* out_hyp = out + (size_t)n * 32;      // N*8
    float* out_spd = out + (size_t)n * 40;      // N*9
    float* out_sph = out + (size_t)n * 49;      // N*8
    float* out_cmb = out + (size_t)n * 57;      // N*23

    float comb[23], hr[8], srd[3], sr[8];

    if (valid) {
        size_t r = (size_t)row;
        float4 eu = *(const float4*)(feat + r * 8);
        float4 mf = *(const float4*)(feat + r * 8 + 4);

        float p[8], sd[3], sp[8];
        compute_base(mf, Wh, bh, Ws, bs, Wp, bp, p, sd, sp);

        // ---------- hyperbolic refinement: hyp_exp(p, 0.1*hyp_log(p, hc)) ----------
        float hc[8];
#pragma unroll
        for (int j = 0; j < 8; ++j) hc[j] = cons[j];
        float nx2 = 0.f;
#pragma unroll
        for (int j = 0; j < 8; ++j) nx2 += p[j] * p[j];
        // mobius_add(-p, hc)
        float xy = 0.f, ny2 = 0.f;
#pragma unroll
        for (int j = 0; j < 8; ++j) { xy -= p[j] * hc[j]; ny2 += hc[j] * hc[j]; }
        float a1 = 1.f + 2.f * xy + ny2;
        float b1 = 1.f - nx2;
        float id1 = 1.f / (1.f + 2.f * xy + nx2 * ny2 + 1e-10f);
        float sub[8]; float ns2 = 0.f;
#pragma unroll
        for (int j = 0; j < 8; ++j) {
            float s = (a1 * (-p[j]) + b1 * hc[j]) * id1;
            sub[j] = s; ns2 += s * s;
        }
        float ns  = fmaxf(sqrtf(ns2), 1e-10f);
        float lam = 2.f / (1.f - nx2);
        float vcoef = 0.1f * fast_atanh01(ns) / (ns * lam * 0.5f);   // 0.1 * log coef
        float v[8]; float nv2 = 0.f;
#pragma unroll
        for (int j = 0; j < 8; ++j) { float t = vcoef * sub[j]; v[j] = t; nv2 += t * t; }
        float nvv = fmaxf(sqrtf(nv2), 1e-10f);
        float ecoef = fast_tanh_pos(lam * nvv * 0.5f) / nvv;
        float y[8]; float xy2 = 0.f, nyy2 = 0.f;
#pragma unroll
        for (int j = 0; j < 8; ++j) { float t = ecoef * v[j]; y[j] = t; xy2 += p[j] * t; nyy2 += t * t; }
        float a2 = 1.f + 2.f * xy2 + nyy2;
        float b2 = 1.f - nx2;
        float id2 = 1.f / (1.f + 2.f * xy2 + nx2 * nyy2 + 1e-10f);
        float hn2 = 0.f;
#pragma unroll
        for (int j = 0; j < 8; ++j) { float t = (a2 * p[j] + b2 * y[j]) * id2; hr[j] = t; hn2 += t * t; }
        float hn = sqrtf(hn2);
        if (hn > 0.99999f) {
            float s = 0.99999f / hn;
#pragma unroll
            for (int j = 0; j < 8; ++j) hr[j] *= s;
        }
        // hyp_pull = hyp_log(0, hr) = atanh(|hr|)/|hr| * hr
        float nsb2 = 0.f;
#pragma unroll
        for (int j = 0; j < 8; ++j) nsb2 += hr[j] * hr[j];
        float nsb = fmaxf(sqrtf(nsb2), 1e-10f);
        float pcoef = fast_atanh01(nsb) / nsb;

        // ---------- spherical refinement: sph_exp(sp, 0.1*sph_log(sp, sc)) ----------
        float scv[8], geo3[3];
#pragma unroll
        for (int j = 0; j < 8; ++j) scv[j] = cons[11 + j];
#pragma unroll
        for (int k = 0; k < 3; ++k) geo3[k] = cons[8 + k];
        float sxy = 0.f;
#pragma unroll
        for (int j = 0; j < 8; ++j) sxy += sp[j] * scv[j];
        sxy = fminf(fmaxf(sxy, -1.f + 1e-6f), 1.f - 1e-6f);
        float svcoef = 0.1f * acosf(sxy) / sqrtf(1.f - sxy * sxy + 1e-10f);
        float sv[8]; float snv2 = 0.f;
#pragma unroll
        for (int j = 0; j < 8; ++j) { float t = svcoef * (scv[j] - sxy * sp[j]); sv[j] = t; snv2 += t * t; }
        float snv = fmaxf(sqrtf(snv2), 1e-10f);
        float cn  = __cosf(snv);
        float sn_ = __sinf(snv) / snv;
        float st[8]; float stn2 = 0.f;
#pragma unroll
        for (int j = 0; j < 8; ++j) { float t = cn * sp[j] + sn_ * sv[j]; st[j] = t; stn2 += t * t; }
        float istn = 1.f / (sqrtf(stn2) + 1e-10f);
#pragma unroll
        for (int j = 0; j < 8; ++j) sr[j] = st[j] * istn;

        // ---------- SPD refinement ----------
#pragma unroll
        for (int k = 0; k < 3; ++k)
            srd[k] = fmaxf(0.9f * sd[k] + 0.1f * geo3[k], 1e-6f);

        // ---------- combined (23) ----------
        comb[0] = eu.x; comb[1] = eu.y; comb[2] = eu.z; comb[3] = eu.w;
#pragma unroll
        for (int j = 0; j < 8; ++j) comb[4 + j] = pcoef * hr[j];
#pragma unroll
        for (int k = 0; k < 3; ++k) comb[12 + k] = __logf(srd[k] + 1e-8f);
#pragma unroll
        for (int j = 0; j < 8; ++j) comb[15 + j] = sr[j];
    }

    // ---------- R-cmb: combined, linear stride-23, REGULAR stores (L2-resident) ----------
    if (valid) {
        float* lrow = sf + tid * 23;
#pragma unroll
        for (int k = 0; k < 23; ++k) lrow[k] = comb[k];
    }
    __syncthreads();
    {
        float* dst = out_cmb + (size_t)blockStart * 23;
        const int E = vr * 23;
        const int E4 = E >> 2;
        float4* dst4 = (float4*)dst;
        for (int i4 = tid; i4 < E4; i4 += BS)
            dst4[i4] = ((const float4*)sf)[i4];
        for (int i = (E4 << 2) + tid; i < E; i += BS)
            dst[i] = sf[i];
    }
    __syncthreads();

    // ---------- R3: spd linear@0 | hyp f4[2][257]@576 | sph f4[2][257]@1090 ----------
    if (valid) {
        float* ls = sf + tid * 9;
        ls[0] = srd[0]; ls[1] = 0.f;    ls[2] = 0.f;
        ls[3] = 0.f;    ls[4] = srd[1]; ls[5] = 0.f;
        ls[6] = 0.f;    ls[7] = 0.f;    ls[8] = srd[2];
        sbuf4[576 + 0 * 257 + tid]  = make_float4(hr[0], hr[1], hr[2], hr[3]);
        sbuf4[576 + 1 * 257 + tid]  = make_float4(hr[4], hr[5], hr[6], hr[7]);
        sbuf4[1090 + 0 * 257 + tid] = make_float4(sr[0], sr[1], sr[2], sr[3]);
        sbuf4[1090 + 1 * 257 + tid] = make_float4(sr[4], sr[5], sr[6], sr[7]);
    }
    __syncthreads();
    {
        float* d1 = out_spd + (size_t)blockStart * 9;
        const int E = vr * 9;
        const int E4 = E >> 2;
        float4* d14 = (float4*)d1;
        for (int i4 = tid; i4 < E4; i4 += BS)
            nts4(d14 + i4, ((const float4*)sf)[i4]);
        for (int i = (E4 << 2) + tid; i < E; i += BS)
            nts1(d1 + i, sf[i]);

        float4* d24 = (float4*)(out_hyp + (size_t)blockStart * 8);
        const int H4 = vr * 2;
        for (int i4 = tid; i4 < H4; i4 += BS)
            nts4(d24 + i4, sbuf4[576 + (i4 & 1) * 257 + (i4 >> 1)]);

        float4* d34 = (float4*)(out_sph + (size_t)blockStart * 8);
        for (int i4 = tid; i4 < H4; i4 += BS)
            nts4(d34 + i4, sbuf4[1090 + (i4 & 1) * 257 + (i4 >> 1)]);
    }
}

// Pass 3b: integrated = relu(comb @ W_int + b_int). Reads comb back (L2/L3-hot),
// LDS-staged coalesced in, scalar-pipe s_load Wi (k-outer -> s_load_dwordx16
// batches), f4-column conflict-free staged NT flush. Lean VGPR, 6 blocks/CU.
__global__ __launch_bounds__(BS) void int_kernel(
    int n,
    const float* __restrict__ Wi, const float* __restrict__ bi,
    float* __restrict__ out)
{
    __shared__ float4 b4[1472];              // 23552 B
    float* bf = (float*)b4;

    const int tid = threadIdx.x;
    const int blockStart = blockIdx.x * BS;
    const int row = blockStart + tid;
    const bool valid = row < n;
    const int vr = min(BS, n - blockStart);

    float* out_int = out;                        // N*32
    const float* out_cmb = out + (size_t)n * 57; // N*23

    // coalesced load of this block's comb rows into LDS (linear)
    {
        const float* src = out_cmb + (size_t)blockStart * 23;
        const int E = vr * 23;
        const int E4 = E >> 2;
        const float4* src4 = (const float4*)src;
        for (int i4 = tid; i4 < E4; i4 += BS) b4[i4] = src4[i4];
        for (int i = (E4 << 2) + tid; i < E; i += BS) bf[i] = src[i];
    }
    __syncthreads();

    float o[32];
    if (valid) {
        float c[23];
#pragma unroll
        for (int k = 0; k < 23; ++k) c[k] = bf[tid * 23 + k];   // 23 coprime 32: conflict-free
#pragma unroll
        for (int j = 0; j < 32; ++j) o[j] = bi[j];
#pragma unroll
        for (int k = 0; k < 23; ++k) {                          // k-outer: Wi row = 32
            float ck = c[k];                                     // consecutive floats ->
#pragma unroll
            for (int j = 0; j < 32; ++j)                         // wide scalar loads
                o[j] += ck * Wi[k * 32 + j];
        }
#pragma unroll
        for (int j = 0; j < 32; ++j) o[j] = fmaxf(o[j], 0.f);
    }

    // stage+flush in two 128-row halves through [8][129] f4 columns (16512 B)
#pragma unroll
    for (int h = 0; h < 2; ++h) {
        __syncthreads();
        if (valid && (tid >> 7) == h) {
            int t = tid & 127;
#pragma unroll
            for (int c4 = 0; c4 < 8; ++c4)
                b4[c4 * 129 + t] = make_float4(o[c4 * 4], o[c4 * 4 + 1],
                                               o[c4 * 4 + 2], o[c4 * 4 + 3]);
        }
        __syncthreads();
        int rows = vr - h * 128;
        rows = rows < 0 ? 0 : (rows > 128 ? 128 : rows);
        float4* dst4 = (float4*)(out_int + (size_t)(blockStart + h * 128) * 32);
        const int E4 = rows * 8;
        for (int i4 = tid; i4 < E4; i4 += BS)
            nts4(dst4 + i4, b4[(i4 & 7) * 129 + (i4 >> 3)]);
    }
}

extern "C" void kernel_launch(void* const* d_in, const int* in_sizes, int n_in,
                              void* d_out, int out_size, void* d_ws, size_t ws_size,
                              hipStream_t stream) {
    const float* feat = (const float*)d_in[0];
    const float* Wh = (const float*)d_in[1];
    const float* bh = (const float*)d_in[2];
    const float* Ws = (const float*)d_in[3];
    const float* bs = (const float*)d_in[4];
    const float* Wp = (const float*)d_in[5];
    const float* bp = (const float*)d_in[6];
    const float* Wi = (const float*)d_in[7];
    const float* bi = (const float*)d_in[8];
    int n = in_sizes[0] / 8;

    float* partials = (float*)d_ws;          // NB1*19 floats
    float* cons = partials + NB1 * 19;       // 19 floats
    float* out = (float*)d_out;

    int nb = (n + BS - 1) / BS;
    reduce_kernel<<<NB1, BS, 0, stream>>>(feat, n, Wh, bh, Ws, bs, Wp, bp, partials);
    finalize_kernel<<<1, 256, 0, stream>>>(partials, cons, n);
    geom_kernel<<<nb, BS, 0, stream>>>(feat, n, Wh, bh, Ws, bs, Wp, bp, cons, out);
    int_kernel<<<nb, BS, 0, stream>>>(n, Wi, bi, out);
}

// Round 4
// 705.846 us; speedup vs baseline: 1.0631x; 1.0631x over previous
//
#include <hip/hip_runtime.h>
#include <math.h>

#define NB1 1024
#define BS  256

typedef float f4v __attribute__((ext_vector_type(4)));

__device__ __forceinline__ void nts4(float4* p, float4 v) {
    __builtin_nontemporal_store(*(const f4v*)&v, (f4v*)p);
}
__device__ __forceinline__ void nts1(float* p, float v) {
    __builtin_nontemporal_store(v, p);
}

// fast transcendentals (args constrained as noted; harness tolerance 0.0625 absmax)
__device__ __forceinline__ float fast_tanh_pos(float x) {   // x >= 0
    float e = __expf(-2.f * x);
    return (1.f - e) / (1.f + e);
}
__device__ __forceinline__ float fast_atanh01(float x) {    // x in [0,1)
    return 0.5f * __logf((1.f + x) / (1.f - x));
}

// Computes per-row base quantities from mf = features[row][4:8]:
//   hp[8]  = hyp_pt   (hyperbolic point, exp-map from origin, projected)
//   sd[3]  = spd_diag (exp(linear)+0.1)
//   sp[8]  = sph_pt   (normalized sphere point)
__device__ __forceinline__ void compute_base(
    const float4 mf,
    const float* __restrict__ Wh, const float* __restrict__ bh,
    const float* __restrict__ Ws, const float* __restrict__ bs,
    const float* __restrict__ Wp, const float* __restrict__ bp,
    float* hp, float* sd, float* sp)
{
    // hyp_tan = mf[0:2] @ W_hyp + b_hyp ; hyp_pt = proj(tanh(|t|)/|t| * t)
    float ht[8];
    float nv2 = 0.f;
#pragma unroll
    for (int j = 0; j < 8; ++j) {
        float t = mf.x * Wh[j] + mf.y * Wh[8 + j] + bh[j];
        ht[j] = t; nv2 += t * t;
    }
    float nv = fmaxf(sqrtf(nv2), 1e-10f);
    float coef = fast_tanh_pos(nv) / nv;  // C=1: tanh(sc*lam*nv/2)/(sc*nv) with lam=2
    float pn2 = 0.f;
#pragma unroll
    for (int j = 0; j < 8; ++j) {
        float p = coef * ht[j];           // mobius_add(0,y)=y/(1+1e-10); den==1 in f32
        hp[j] = p; pn2 += p * p;
    }
    float pn = sqrtf(pn2);
    if (pn > 0.99999f) {                  // _hyp_proj, max_norm=(1-1e-5)
        float s = 0.99999f / pn;
#pragma unroll
        for (int j = 0; j < 8; ++j) hp[j] *= s;
    }
    // spd_diag = exp(mf[0:3] @ W_spd + b_spd) + 0.1
#pragma unroll
    for (int k = 0; k < 3; ++k) {
        float t = mf.x * Ws[k] + mf.y * Ws[3 + k] + mf.z * Ws[6 + k] + bs[k];
        sd[k] = __expf(t) + 0.1f;
    }
    // sph_pt = proj(mf[2:4] @ W_sph + b_sph)
    float sl[8]; float sn2 = 0.f;
#pragma unroll
    for (int j = 0; j < 8; ++j) {
        float t = mf.z * Wp[j] + mf.w * Wp[8 + j] + bp[j];
        sl[j] = t; sn2 += t * t;
    }
    float isn = 1.0f / (sqrtf(sn2) + 1e-10f);
#pragma unroll
    for (int j = 0; j < 8; ++j) sp[j] = sl[j] * isn;
}

// Pass 1: per-block partial sums of [hyp_pt(8), log(spd_diag+1e-8)(3), sph_pt(8)]
__global__ __launch_bounds__(BS) void reduce_kernel(
    const float* __restrict__ feat, int n,
    const float* __restrict__ Wh, const float* __restrict__ bh,
    const float* __restrict__ Ws, const float* __restrict__ bs,
    const float* __restrict__ Wp, const float* __restrict__ bp,
    float* __restrict__ partials)
{
    float acc[19];
#pragma unroll
    for (int i = 0; i < 19; ++i) acc[i] = 0.f;
    int stride = gridDim.x * blockDim.x;
    for (int row = blockIdx.x * blockDim.x + threadIdx.x; row < n; row += stride) {
        float4 mf = *(const float4*)(feat + (size_t)row * 8 + 4);
        float hp[8], sd[3], sp[8];
        compute_base(mf, Wh, bh, Ws, bs, Wp, bp, hp, sd, sp);
#pragma unroll
        for (int j = 0; j < 8; ++j) acc[j] += hp[j];
#pragma unroll
        for (int k = 0; k < 3; ++k) acc[8 + k] += __logf(sd[k] + 1e-8f);
#pragma unroll
        for (int j = 0; j < 8; ++j) acc[11 + j] += sp[j];
    }
#pragma unroll
    for (int i = 0; i < 19; ++i) {
#pragma unroll
        for (int off = 32; off >= 1; off >>= 1)
            acc[i] += __shfl_down(acc[i], off, 64);
    }
    __shared__ float red[4][19];
    int lane = threadIdx.x & 63, wid = threadIdx.x >> 6;
    if (lane == 0) {
#pragma unroll
        for (int i = 0; i < 19; ++i) red[wid][i] = acc[i];
    }
    __syncthreads();
    if (threadIdx.x < 19) {
        float s = red[0][threadIdx.x] + red[1][threadIdx.x] +
                  red[2][threadIdx.x] + red[3][threadIdx.x];
        partials[(size_t)blockIdx.x * 19 + threadIdx.x] = s;
    }
}

// Pass 2: f64 finalize of the three means -> 19 constants:
//   cons[0:8]=hc (hyp_proj of mean), cons[8:11]=geo_mean, cons[11:19]=sc (sph_proj of mean)
__global__ void finalize_kernel(const float* __restrict__ partials,
                                float* __restrict__ cons, int n)
{
    __shared__ double ms[19];
    int tid = threadIdx.x;
    int k = tid >> 3, w = tid & 7;
    if (k < 19) {
        double s = 0.0;
        for (int b = w; b < NB1; b += 8) s += (double)partials[(size_t)b * 19 + k];
#pragma unroll
        for (int off = 4; off >= 1; off >>= 1) s += __shfl_down(s, off, 8);
        if (w == 0) ms[k] = s / (double)n;
    }
    __syncthreads();
    if (tid == 0) {
        double hn2 = 0.0;
        for (int j = 0; j < 8; ++j) hn2 += ms[j] * ms[j];
        double hn = sqrt(hn2);
        double sch = (hn > 0.99999) ? (0.99999 / hn) : 1.0;
        for (int j = 0; j < 8; ++j) cons[j] = (float)(ms[j] * sch);
        for (int kk = 0; kk < 3; ++kk) cons[8 + kk] = (float)exp(ms[8 + kk]);
        double sn2 = 0.0;
        for (int j = 0; j < 8; ++j) sn2 += ms[11 + j] * ms[11 + j];
        double sn = sqrt(sn2) + 1e-10;
        for (int j = 0; j < 8; ++j) cons[11 + j] = (float)(ms[11 + j] / sn);
    }
}

// Pass 3: monolithic per-row computation + all outputs (comb lives in registers,
// never re-read from memory). All flushes float4 NON-TEMPORAL stores fed by
// conflict-free LDS layouts:
//   R1: integrated 32f -> f4 columns [8][257]  (stage & flush conflict-free)
//   R2: combined 23f   -> linear (23 coprime 32; b128 flush reads)
//   R3: spd 9f linear | hyp f4[2][257] | sph f4[2][257]
// W_int/b_int are read DIRECTLY from global with wave-uniform indices ->
// scalar-pipe s_load (co-issues with VALU; L1-scalar-hot). No LDS for weights.
__global__ __launch_bounds__(BS) void main_kernel(
    const float* __restrict__ feat, int n,
    const float* __restrict__ Wh, const float* __restrict__ bh,
    const float* __restrict__ Ws, const float* __restrict__ bs,
    const float* __restrict__ Wp, const float* __restrict__ bp,
    const float* __restrict__ cons,
    const float* __restrict__ Wi, const float* __restrict__ bi,
    float* __restrict__ out)
{
    __shared__ float4 sbuf4[8 * 257];        // 32896 B, unioned across rounds
    float* sf = (float*)sbuf4;

    const int tid = threadIdx.x;
    const int blockStart = blockIdx.x * BS;
    const int row = blockStart + tid;
    const bool valid = row < n;
    const int vr = min(BS, n - blockStart);  // valid rows in this block

    float* out_int = out;                       // N*32
    float* out_hyp = out + (size_t)n * 32;      // N*8
    float* out_spd = out + (size_t)n * 40;      // N*9
    float* out_sph = out + (size_t)n * 49;      // N*8
    float* out_cmb = out + (size_t)n * 57;      // N*23

    float comb[23], hr[8], srd[3], sr[8];

    if (valid) {
        size_t r = (size_t)row;
        float4 eu = *(const float4*)(feat + r * 8);
        float4 mf = *(const float4*)(feat + r * 8 + 4);

        float p[8], sd[3], sp[8];
        compute_base(mf, Wh, bh, Ws, bs, Wp, bp, p, sd, sp);

        // ---------- hyperbolic refinement: hyp_exp(p, 0.1*hyp_log(p, hc)) ----------
        float hc[8];
#pragma unroll
        for (int j = 0; j < 8; ++j) hc[j] = cons[j];
        float nx2 = 0.f;
#pragma unroll
        for (int j = 0; j < 8; ++j) nx2 += p[j] * p[j];
        // mobius_add(-p, hc)
        float xy = 0.f, ny2 = 0.f;
#pragma unroll
        for (int j = 0; j < 8; ++j) { xy -= p[j] * hc[j]; ny2 += hc[j] * hc[j]; }
        float a1 = 1.f + 2.f * xy + ny2;
        float b1 = 1.f - nx2;
        float id1 = 1.f / (1.f + 2.f * xy + nx2 * ny2 + 1e-10f);
        float sub[8]; float ns2 = 0.f;
#pragma unroll
        for (int j = 0; j < 8; ++j) {
            float s = (a1 * (-p[j]) + b1 * hc[j]) * id1;
            sub[j] = s; ns2 += s * s;
        }
        float ns  = fmaxf(sqrtf(ns2), 1e-10f);
        float lam = 2.f / (1.f - nx2);
        float vcoef = 0.1f * fast_atanh01(ns) / (ns * lam * 0.5f);   // 0.1 * log coef
        float v[8]; float nv2 = 0.f;
#pragma unroll
        for (int j = 0; j < 8; ++j) { float t = vcoef * sub[j]; v[j] = t; nv2 += t * t; }
        float nvv = fmaxf(sqrtf(nv2), 1e-10f);
        float ecoef = fast_tanh_pos(lam * nvv * 0.5f) / nvv;
        float y[8]; float xy2 = 0.f, nyy2 = 0.f;
#pragma unroll
        for (int j = 0; j < 8; ++j) { float t = ecoef * v[j]; y[j] = t; xy2 += p[j] * t; nyy2 += t * t; }
        float a2 = 1.f + 2.f * xy2 + nyy2;
        float b2 = 1.f - nx2;
        float id2 = 1.f / (1.f + 2.f * xy2 + nx2 * nyy2 + 1e-10f);
        float hn2 = 0.f;
#pragma unroll
        for (int j = 0; j < 8; ++j) { float t = (a2 * p[j] + b2 * y[j]) * id2; hr[j] = t; hn2 += t * t; }
        float hn = sqrtf(hn2);
        if (hn > 0.99999f) {
            float s = 0.99999f / hn;
#pragma unroll
            for (int j = 0; j < 8; ++j) hr[j] *= s;
        }
        // hyp_pull = hyp_log(0, hr) = atanh(|hr|)/|hr| * hr
        float nsb2 = 0.f;
#pragma unroll
        for (int j = 0; j < 8; ++j) nsb2 += hr[j] * hr[j];
        float nsb = fmaxf(sqrtf(nsb2), 1e-10f);
        float pcoef = fast_atanh01(nsb) / nsb;

        // ---------- spherical refinement: sph_exp(sp, 0.1*sph_log(sp, sc)) ----------
        float scv[8], geo3[3];
#pragma unroll
        for (int j = 0; j < 8; ++j) scv[j] = cons[11 + j];
#pragma unroll
        for (int k = 0; k < 3; ++k) geo3[k] = cons[8 + k];
        float sxy = 0.f;
#pragma unroll
        for (int j = 0; j < 8; ++j) sxy += sp[j] * scv[j];
        sxy = fminf(fmaxf(sxy, -1.f + 1e-6f), 1.f - 1e-6f);
        float svcoef = 0.1f * acosf(sxy) / sqrtf(1.f - sxy * sxy + 1e-10f);
        float sv[8]; float snv2 = 0.f;
#pragma unroll
        for (int j = 0; j < 8; ++j) { float t = svcoef * (scv[j] - sxy * sp[j]); sv[j] = t; snv2 += t * t; }
        float snv = fmaxf(sqrtf(snv2), 1e-10f);
        float cn  = __cosf(snv);
        float sn_ = __sinf(snv) / snv;
        float st[8]; float stn2 = 0.f;
#pragma unroll
        for (int j = 0; j < 8; ++j) { float t = cn * sp[j] + sn_ * sv[j]; st[j] = t; stn2 += t * t; }
        float istn = 1.f / (sqrtf(stn2) + 1e-10f);
#pragma unroll
        for (int j = 0; j < 8; ++j) sr[j] = st[j] * istn;

        // ---------- SPD refinement ----------
#pragma unroll
        for (int k = 0; k < 3; ++k)
            srd[k] = fmaxf(0.9f * sd[k] + 0.1f * geo3[k], 1e-6f);

        // ---------- combined (23) ----------
        comb[0] = eu.x; comb[1] = eu.y; comb[2] = eu.z; comb[3] = eu.w;
#pragma unroll
        for (int j = 0; j < 8; ++j) comb[4 + j] = pcoef * hr[j];
#pragma unroll
        for (int k = 0; k < 3; ++k) comb[12 + k] = __logf(srd[k] + 1e-8f);
#pragma unroll
        for (int j = 0; j < 8; ++j) comb[15 + j] = sr[j];
    }

    // ---------- R1: integrated = relu(comb @ W_int + b_int), f4 cols [8][257] ----------
    // Wi/bi indices are wave-uniform -> scalar-pipe s_load (dwordx4 per k per c4)
    if (valid) {
#pragma unroll
        for (int c4 = 0; c4 < 8; ++c4) {
            float a_[4];
#pragma unroll
            for (int jj = 0; jj < 4; ++jj) a_[jj] = bi[c4 * 4 + jj];
#pragma unroll
            for (int k2 = 0; k2 < 23; ++k2) {
                float ck = comb[k2];
#pragma unroll
                for (int jj = 0; jj < 4; ++jj)
                    a_[jj] += ck * Wi[k2 * 32 + c4 * 4 + jj];
            }
            sbuf4[c4 * 257 + tid] = make_float4(fmaxf(a_[0], 0.f), fmaxf(a_[1], 0.f),
                                                fmaxf(a_[2], 0.f), fmaxf(a_[3], 0.f));
        }
    }
    __syncthreads();
    {
        float4* dst4 = (float4*)(out_int + (size_t)blockStart * 32);
        const int E4 = vr * 8;
        for (int i4 = tid; i4 < E4; i4 += BS)
            nts4(dst4 + i4, sbuf4[(i4 & 7) * 257 + (i4 >> 3)]);
    }
    __syncthreads();

    // ---------- R2: combined, linear stride-23 ----------
    if (valid) {
        float* lrow = sf + tid * 23;
#pragma unroll
        for (int k = 0; k < 23; ++k) lrow[k] = comb[k];
    }
    __syncthreads();
    {
        float* dst = out_cmb + (size_t)blockStart * 23;
        const int E = vr * 23;
        const int E4 = E >> 2;
        float4* dst4 = (float4*)dst;
        for (int i4 = tid; i4 < E4; i4 += BS)
            nts4(dst4 + i4, ((const float4*)sf)[i4]);
        for (int i = (E4 << 2) + tid; i < E; i += BS)
            nts1(dst + i, sf[i]);
    }
    __syncthreads();

    // ---------- R3: spd linear@0 | hyp f4[2][257]@576 | sph f4[2][257]@1090 ----------
    if (valid) {
        float* ls = sf + tid * 9;
        ls[0] = srd[0]; ls[1] = 0.f;    ls[2] = 0.f;
        ls[3] = 0.f;    ls[4] = srd[1]; ls[5] = 0.f;
        ls[6] = 0.f;    ls[7] = 0.f;    ls[8] = srd[2];
        sbuf4[576 + 0 * 257 + tid]  = make_float4(hr[0], hr[1], hr[2], hr[3]);
        sbuf4[576 + 1 * 257 + tid]  = make_float4(hr[4], hr[5], hr[6], hr[7]);
        sbuf4[1090 + 0 * 257 + tid] = make_float4(sr[0], sr[1], sr[2], sr[3]);
        sbuf4[1090 + 1 * 257 + tid] = make_float4(sr[4], sr[5], sr[6], sr[7]);
    }
    __syncthreads();
    {
        float* d1 = out_spd + (size_t)blockStart * 9;
        const int E = vr * 9;
        const int E4 = E >> 2;
        float4* d14 = (float4*)d1;
        for (int i4 = tid; i4 < E4; i4 += BS)
            nts4(d14 + i4, ((const float4*)sf)[i4]);
        for (int i = (E4 << 2) + tid; i < E; i += BS)
            nts1(d1 + i, sf[i]);

        float4* d24 = (float4*)(out_hyp + (size_t)blockStart * 8);
        const int H4 = vr * 2;
        for (int i4 = tid; i4 < H4; i4 += BS)
            nts4(d24 + i4, sbuf4[576 + (i4 & 1) * 257 + (i4 >> 1)]);

        float4* d34 = (float4*)(out_sph + (size_t)blockStart * 8);
        for (int i4 = tid; i4 < H4; i4 += BS)
            nts4(d34 + i4, sbuf4[1090 + (i4 & 1) * 257 + (i4 >> 1)]);
    }
}

extern "C" void kernel_launch(void* const* d_in, const int* in_sizes, int n_in,
                              void* d_out, int out_size, void* d_ws, size_t ws_size,
                              hipStream_t stream) {
    const float* feat = (const float*)d_in[0];
    const float* Wh = (const float*)d_in[1];
    const float* bh = (const float*)d_in[2];
    const float* Ws = (const float*)d_in[3];
    const float* bs = (const float*)d_in[4];
    const float* Wp = (const float*)d_in[5];
    const float* bp = (const float*)d_in[6];
    const float* Wi = (const float*)d_in[7];
    const float* bi = (const float*)d_in[8];
    int n = in_sizes[0] / 8;

    float* partials = (float*)d_ws;          // NB1*19 floats
    float* cons = partials + NB1 * 19;       // 19 floats
    float* out = (float*)d_out;

    reduce_kernel<<<NB1, BS, 0, stream>>>(feat, n, Wh, bh, Ws, bs, Wp, bp, partials);
    finalize_kernel<<<1, 256, 0, stream>>>(partials, cons, n);
    main_kernel<<<(n + BS - 1) / BS, BS, 0, stream>>>(feat, n, Wh, bh, Ws, bs, Wp, bp,
                                                      cons, Wi, bi, out);
}

// Round 5
// 700.257 us; speedup vs baseline: 1.0716x; 1.0080x over previous
//
#include <hip/hip_runtime.h>
#include <math.h>

#define NB1 1024
#define BS  256

typedef float f4v __attribute__((ext_vector_type(4)));

__device__ __forceinline__ void nts4(float4* p, float4 v) {
    __builtin_nontemporal_store(*(const f4v*)&v, (f4v*)p);
}
__device__ __forceinline__ void nts1(float* p, float v) {
    __builtin_nontemporal_store(v, p);
}

// wave-local LDS fence: all my LDS ops done, compiler may not reorder across
#define WAVE_LDS_FENCE() asm volatile("s_waitcnt lgkmcnt(0)" ::: "memory")

// fast transcendentals (args constrained as noted; harness tolerance 0.0625 absmax)
__device__ __forceinline__ float fast_tanh_pos(float x) {   // x >= 0
    float e = __expf(-2.f * x);
    return (1.f - e) / (1.f + e);
}
__device__ __forceinline__ float fast_atanh01(float x) {    // x in [0,1)
    return 0.5f * __logf((1.f + x) / (1.f - x));
}

// Computes per-row base quantities from mf = features[row][4:8]:
//   hp[8]  = hyp_pt   (hyperbolic point, exp-map from origin, projected)
//   sd[3]  = spd_diag (exp(linear)+0.1)
//   sp[8]  = sph_pt   (normalized sphere point)
__device__ __forceinline__ void compute_base(
    const float4 mf,
    const float* __restrict__ Wh, const float* __restrict__ bh,
    const float* __restrict__ Ws, const float* __restrict__ bs,
    const float* __restrict__ Wp, const float* __restrict__ bp,
    float* hp, float* sd, float* sp)
{
    // hyp_tan = mf[0:2] @ W_hyp + b_hyp ; hyp_pt = proj(tanh(|t|)/|t| * t)
    float ht[8];
    float nv2 = 0.f;
#pragma unroll
    for (int j = 0; j < 8; ++j) {
        float t = mf.x * Wh[j] + mf.y * Wh[8 + j] + bh[j];
        ht[j] = t; nv2 += t * t;
    }
    float nv = fmaxf(sqrtf(nv2), 1e-10f);
    float coef = fast_tanh_pos(nv) / nv;  // C=1: tanh(sc*lam*nv/2)/(sc*nv) with lam=2
    float pn2 = 0.f;
#pragma unroll
    for (int j = 0; j < 8; ++j) {
        float p = coef * ht[j];           // mobius_add(0,y)=y/(1+1e-10); den==1 in f32
        hp[j] = p; pn2 += p * p;
    }
    float pn = sqrtf(pn2);
    if (pn > 0.99999f) {                  // _hyp_proj, max_norm=(1-1e-5)
        float s = 0.99999f / pn;
#pragma unroll
        for (int j = 0; j < 8; ++j) hp[j] *= s;
    }
    // spd_diag = exp(mf[0:3] @ W_spd + b_spd) + 0.1
#pragma unroll
    for (int k = 0; k < 3; ++k) {
        float t = mf.x * Ws[k] + mf.y * Ws[3 + k] + mf.z * Ws[6 + k] + bs[k];
        sd[k] = __expf(t) + 0.1f;
    }
    // sph_pt = proj(mf[2:4] @ W_sph + b_sph)
    float sl[8]; float sn2 = 0.f;
#pragma unroll
    for (int j = 0; j < 8; ++j) {
        float t = mf.z * Wp[j] + mf.w * Wp[8 + j] + bp[j];
        sl[j] = t; sn2 += t * t;
    }
    float isn = 1.0f / (sqrtf(sn2) + 1e-10f);
#pragma unroll
    for (int j = 0; j < 8; ++j) sp[j] = sl[j] * isn;
}

// Pass 1: per-block partial sums of [hyp_pt(8), log(spd_diag+1e-8)(3), sph_pt(8)]
__global__ __launch_bounds__(BS) void reduce_kernel(
    const float* __restrict__ feat, int n,
    const float* __restrict__ Wh, const float* __restrict__ bh,
    const float* __restrict__ Ws, const float* __restrict__ bs,
    const float* __restrict__ Wp, const float* __restrict__ bp,
    float* __restrict__ partials)
{
    float acc[19];
#pragma unroll
    for (int i = 0; i < 19; ++i) acc[i] = 0.f;
    int stride = gridDim.x * blockDim.x;
    for (int row = blockIdx.x * blockDim.x + threadIdx.x; row < n; row += stride) {
        float4 mf = *(const float4*)(feat + (size_t)row * 8 + 4);
        float hp[8], sd[3], sp[8];
        compute_base(mf, Wh, bh, Ws, bs, Wp, bp, hp, sd, sp);
#pragma unroll
        for (int j = 0; j < 8; ++j) acc[j] += hp[j];
#pragma unroll
        for (int k = 0; k < 3; ++k) acc[8 + k] += __logf(sd[k] + 1e-8f);
#pragma unroll
        for (int j = 0; j < 8; ++j) acc[11 + j] += sp[j];
    }
#pragma unroll
    for (int i = 0; i < 19; ++i) {
#pragma unroll
        for (int off = 32; off >= 1; off >>= 1)
            acc[i] += __shfl_down(acc[i], off, 64);
    }
    __shared__ float red[4][19];
    int lane = threadIdx.x & 63, wid = threadIdx.x >> 6;
    if (lane == 0) {
#pragma unroll
        for (int i = 0; i < 19; ++i) red[wid][i] = acc[i];
    }
    __syncthreads();
    if (threadIdx.x < 19) {
        float s = red[0][threadIdx.x] + red[1][threadIdx.x] +
                  red[2][threadIdx.x] + red[3][threadIdx.x];
        partials[(size_t)blockIdx.x * 19 + threadIdx.x] = s;
    }
}

// Pass 2: f64 finalize of the three means -> 19 constants:
//   cons[0:8]=hc (hyp_proj of mean), cons[8:11]=geo_mean, cons[11:19]=sc (sph_proj of mean)
__global__ void finalize_kernel(const float* __restrict__ partials,
                                float* __restrict__ cons, int n)
{
    __shared__ double ms[19];
    int tid = threadIdx.x;
    int k = tid >> 3, w = tid & 7;
    if (k < 19) {
        double s = 0.0;
        for (int b = w; b < NB1; b += 8) s += (double)partials[(size_t)b * 19 + k];
#pragma unroll
        for (int off = 4; off >= 1; off >>= 1) s += __shfl_down(s, off, 8);
        if (w == 0) ms[k] = s / (double)n;
    }
    __syncthreads();
    if (tid == 0) {
        double hn2 = 0.0;
        for (int j = 0; j < 8; ++j) hn2 += ms[j] * ms[j];
        double hn = sqrt(hn2);
        double sch = (hn > 0.99999) ? (0.99999 / hn) : 1.0;
        for (int j = 0; j < 8; ++j) cons[j] = (float)(ms[j] * sch);
        for (int kk = 0; kk < 3; ++kk) cons[8 + kk] = (float)exp(ms[8 + kk]);
        double sn2 = 0.0;
        for (int j = 0; j < 8; ++j) sn2 += ms[11 + j] * ms[11 + j];
        double sn = sqrt(sn2) + 1e-10;
        for (int j = 0; j < 8; ++j) cons[11 + j] = (float)(ms[11 + j] / sn);
    }
}

// Pass 3: monolithic per-row computation + all outputs.
// ZERO barriers: each wave owns a private 520-float4 LDS slice and transposes
// its own 64 rows through it; cross-lane visibility within a wave needs only
// s_waitcnt lgkmcnt(0) (no s_barrier -> no vmcnt(0) store-drain ever; NT stores
// from all rounds pipeline until kernel end). Layouts (per wave slice):
//   R1: integrated 32f -> f4 columns [8][65]  (stage & flush conflict-free,
//       same bank residues as the measured-clean [8][257] block layout)
//   R2: combined 23f   -> linear rows (23 coprime 32; b128 flush reads)
//   R3: spd 9f linear @0 | hyp f4 [2][65] @144 | sph f4 [2][65] @274
// Wi/bi read directly from global, wave-uniform -> scalar-pipe s_load.
__global__ __launch_bounds__(BS) void main_kernel(
    const float* __restrict__ feat, int n,
    const float* __restrict__ Wh, const float* __restrict__ bh,
    const float* __restrict__ Ws, const float* __restrict__ bs,
    const float* __restrict__ Wp, const float* __restrict__ bp,
    const float* __restrict__ cons,
    const float* __restrict__ Wi, const float* __restrict__ bi,
    float* __restrict__ out)
{
    __shared__ float4 sb4[4 * 520];          // 33280 B = 4 waves x 8320 B
    const int tid = threadIdx.x;
    const int lane = tid & 63;
    const int wid = tid >> 6;
    const int blockStart = blockIdx.x * BS;
    const int waveStart = blockStart + wid * 64;
    if (waveStart >= n) return;              // legal: no barriers anywhere below
    const int wrows = min(64, n - waveStart);
    const int row = waveStart + lane;
    const bool valid = row < n;

    float4* slice4 = sb4 + wid * 520;
    float*  sf     = (float*)slice4;

    float* out_int = out;                       // N*32
    float* out_hyp = out + (size_t)n * 32;      // N*8
    float* out_spd = out + (size_t)n * 40;      // N*9
    float* out_sph = out + (size_t)n * 49;      // N*8
    float* out_cmb = out + (size_t)n * 57;      // N*23

    float comb[23], hr[8], srd[3], sr[8];

    if (valid) {
        size_t r = (size_t)row;
        float4 eu = *(const float4*)(feat + r * 8);
        float4 mf = *(const float4*)(feat + r * 8 + 4);

        float p[8], sd[3], sp[8];
        compute_base(mf, Wh, bh, Ws, bs, Wp, bp, p, sd, sp);

        // ---------- hyperbolic refinement: hyp_exp(p, 0.1*hyp_log(p, hc)) ----------
        float hc[8];
#pragma unroll
        for (int j = 0; j < 8; ++j) hc[j] = cons[j];
        float nx2 = 0.f;
#pragma unroll
        for (int j = 0; j < 8; ++j) nx2 += p[j] * p[j];
        // mobius_add(-p, hc)
        float xy = 0.f, ny2 = 0.f;
#pragma unroll
        for (int j = 0; j < 8; ++j) { xy -= p[j] * hc[j]; ny2 += hc[j] * hc[j]; }
        float a1 = 1.f + 2.f * xy + ny2;
        float b1 = 1.f - nx2;
        float id1 = 1.f / (1.f + 2.f * xy + nx2 * ny2 + 1e-10f);
        float sub[8]; float ns2 = 0.f;
#pragma unroll
        for (int j = 0; j < 8; ++j) {
            float s = (a1 * (-p[j]) + b1 * hc[j]) * id1;
            sub[j] = s; ns2 += s * s;
        }
        float ns  = fmaxf(sqrtf(ns2), 1e-10f);
        float lam = 2.f / (1.f - nx2);
        float vcoef = 0.1f * fast_atanh01(ns) / (ns * lam * 0.5f);   // 0.1 * log coef
        float v[8]; float nv2 = 0.f;
#pragma unroll
        for (int j = 0; j < 8; ++j) { float t = vcoef * sub[j]; v[j] = t; nv2 += t * t; }
        float nvv = fmaxf(sqrtf(nv2), 1e-10f);
        float ecoef = fast_tanh_pos(lam * nvv * 0.5f) / nvv;
        float y[8]; float xy2 = 0.f, nyy2 = 0.f;
#pragma unroll
        for (int j = 0; j < 8; ++j) { float t = ecoef * v[j]; y[j] = t; xy2 += p[j] * t; nyy2 += t * t; }
        float a2 = 1.f + 2.f * xy2 + nyy2;
        float b2 = 1.f - nx2;
        float id2 = 1.f / (1.f + 2.f * xy2 + nx2 * nyy2 + 1e-10f);
        float hn2 = 0.f;
#pragma unroll
        for (int j = 0; j < 8; ++j) { float t = (a2 * p[j] + b2 * y[j]) * id2; hr[j] = t; hn2 += t * t; }
        float hn = sqrtf(hn2);
        if (hn > 0.99999f) {
            float s = 0.99999f / hn;
#pragma unroll
            for (int j = 0; j < 8; ++j) hr[j] *= s;
        }
        // hyp_pull = hyp_log(0, hr) = atanh(|hr|)/|hr| * hr
        float nsb2 = 0.f;
#pragma unroll
        for (int j = 0; j < 8; ++j) nsb2 += hr[j] * hr[j];
        float nsb = fmaxf(sqrtf(nsb2), 1e-10f);
        float pcoef = fast_atanh01(nsb) / nsb;

        // ---------- spherical refinement: sph_exp(sp, 0.1*sph_log(sp, sc)) ----------
        float scv[8], geo3[3];
#pragma unroll
        for (int j = 0; j < 8; ++j) scv[j] = cons[11 + j];
#pragma unroll
        for (int k = 0; k < 3; ++k) geo3[k] = cons[8 + k];
        float sxy = 0.f;
#pragma unroll
        for (int j = 0; j < 8; ++j) sxy += sp[j] * scv[j];
        sxy = fminf(fmaxf(sxy, -1.f + 1e-6f), 1.f - 1e-6f);
        float svcoef = 0.1f * acosf(sxy) / sqrtf(1.f - sxy * sxy + 1e-10f);
        float sv[8]; float snv2 = 0.f;
#pragma unroll
        for (int j = 0; j < 8; ++j) { float t = svcoef * (scv[j] - sxy * sp[j]); sv[j] = t; snv2 += t * t; }
        float snv = fmaxf(sqrtf(snv2), 1e-10f);
        float cn  = __cosf(snv);
        float sn_ = __sinf(snv) / snv;
        float st[8]; float stn2 = 0.f;
#pragma unroll
        for (int j = 0; j < 8; ++j) { float t = cn * sp[j] + sn_ * sv[j]; st[j] = t; stn2 += t * t; }
        float istn = 1.f / (sqrtf(stn2) + 1e-10f);
#pragma unroll
        for (int j = 0; j < 8; ++j) sr[j] = st[j] * istn;

        // ---------- SPD refinement ----------
#pragma unroll
        for (int k = 0; k < 3; ++k)
            srd[k] = fmaxf(0.9f * sd[k] + 0.1f * geo3[k], 1e-6f);

        // ---------- combined (23) ----------
        comb[0] = eu.x; comb[1] = eu.y; comb[2] = eu.z; comb[3] = eu.w;
#pragma unroll
        for (int j = 0; j < 8; ++j) comb[4 + j] = pcoef * hr[j];
#pragma unroll
        for (int k = 0; k < 3; ++k) comb[12 + k] = __logf(srd[k] + 1e-8f);
#pragma unroll
        for (int j = 0; j < 8; ++j) comb[15 + j] = sr[j];
    }

    // ---------- R1: integrated = relu(comb @ W_int + b_int), f4 cols [8][65] ----------
    if (valid) {
#pragma unroll
        for (int c4 = 0; c4 < 8; ++c4) {
            float a_[4];
#pragma unroll
            for (int jj = 0; jj < 4; ++jj) a_[jj] = bi[c4 * 4 + jj];
#pragma unroll
            for (int k2 = 0; k2 < 23; ++k2) {
                float ck = comb[k2];
#pragma unroll
                for (int jj = 0; jj < 4; ++jj)
                    a_[jj] += ck * Wi[k2 * 32 + c4 * 4 + jj];
            }
            slice4[c4 * 65 + lane] = make_float4(fmaxf(a_[0], 0.f), fmaxf(a_[1], 0.f),
                                                 fmaxf(a_[2], 0.f), fmaxf(a_[3], 0.f));
        }
    }
    WAVE_LDS_FENCE();
    {
        float4* dst4 = (float4*)(out_int + (size_t)waveStart * 32);
        const int E4 = wrows * 8;
        for (int i4 = lane; i4 < E4; i4 += 64)
            nts4(dst4 + i4, slice4[(i4 & 7) * 65 + (i4 >> 3)]);
    }
    WAVE_LDS_FENCE();

    // ---------- R2: combined, linear rows stride-23 ----------
    if (valid) {
        float* lrow = sf + lane * 23;
#pragma unroll
        for (int k = 0; k < 23; ++k) lrow[k] = comb[k];
    }
    WAVE_LDS_FENCE();
    {
        float* dst = out_cmb + (size_t)waveStart * 23;
        const int E = wrows * 23;
        const int E4 = E >> 2;
        float4* dst4 = (float4*)dst;
        for (int i4 = lane; i4 < E4; i4 += 64)
            nts4(dst4 + i4, ((const float4*)sf)[i4]);
        for (int i = (E4 << 2) + lane; i < E; i += 64)
            nts1(dst + i, sf[i]);
    }
    WAVE_LDS_FENCE();

    // ---------- R3: spd linear @0 | hyp f4[2][65] @144 | sph f4[2][65] @274 ----------
    if (valid) {
        float* ls = sf + lane * 9;
        ls[0] = srd[0]; ls[1] = 0.f;    ls[2] = 0.f;
        ls[3] = 0.f;    ls[4] = srd[1]; ls[5] = 0.f;
        ls[6] = 0.f;    ls[7] = 0.f;    ls[8] = srd[2];
        slice4[144 + 0 * 65 + lane] = make_float4(hr[0], hr[1], hr[2], hr[3]);
        slice4[144 + 1 * 65 + lane] = make_float4(hr[4], hr[5], hr[6], hr[7]);
        slice4[274 + 0 * 65 + lane] = make_float4(sr[0], sr[1], sr[2], sr[3]);
        slice4[274 + 1 * 65 + lane] = make_float4(sr[4], sr[5], sr[6], sr[7]);
    }
    WAVE_LDS_FENCE();
    {
        float* d1 = out_spd + (size_t)waveStart * 9;
        const int E = wrows * 9;
        const int E4 = E >> 2;
        float4* d14 = (float4*)d1;
        for (int i4 = lane; i4 < E4; i4 += 64)
            nts4(d14 + i4, ((const float4*)sf)[i4]);
        for (int i = (E4 << 2) + lane; i < E; i += 64)
            nts1(d1 + i, sf[i]);

        float4* d24 = (float4*)(out_hyp + (size_t)waveStart * 8);
        const int H4 = wrows * 2;
        for (int i4 = lane; i4 < H4; i4 += 64)
            nts4(d24 + i4, slice4[144 + (i4 & 1) * 65 + (i4 >> 1)]);

        float4* d34 = (float4*)(out_sph + (size_t)waveStart * 8);
        for (int i4 = lane; i4 < H4; i4 += 64)
            nts4(d34 + i4, slice4[274 + (i4 & 1) * 65 + (i4 >> 1)]);
    }
}

extern "C" void kernel_launch(void* const* d_in, const int* in_sizes, int n_in,
                              void* d_out, int out_size, void* d_ws, size_t ws_size,
                              hipStream_t stream) {
    const float* feat = (const float*)d_in[0];
    const float* Wh = (const float*)d_in[1];
    const float* bh = (const float*)d_in[2];
    const float* Ws = (const float*)d_in[3];
    const float* bs = (const float*)d_in[4];
    const float* Wp = (const float*)d_in[5];
    const float* bp = (const float*)d_in[6];
    const float* Wi = (const float*)d_in[7];
    const float* bi = (const float*)d_in[8];
    int n = in_sizes[0] / 8;

    float* partials = (float*)d_ws;          // NB1*19 floats
    float* cons = partials + NB1 * 19;       // 19 floats
    float* out = (float*)d_out;

    reduce_kernel<<<NB1, BS, 0, stream>>>(feat, n, Wh, bh, Ws, bs, Wp, bp, partials);
    finalize_kernel<<<1, 256, 0, stream>>>(partials, cons, n);
    main_kernel<<<(n + BS - 1) / BS, BS, 0, stream>>>(feat, n, Wh, bh, Ws, bs, Wp, bp,
                                                      cons, Wi, bi, out);
}